// Round 1
// baseline (334.692 us; speedup 1.0000x reference)
//
#include <hip/hip_runtime.h>
#include <hip/hip_bf16.h>

#define T_TOK 2048
#define H_DIM 1024
#define E_NUM 16
#define I_DIM 512
#define K_TOP 4
#define SI_DIM 1024

typedef __bf16 bf16x8 __attribute__((ext_vector_type(8)));
typedef __bf16 bf16x4 __attribute__((ext_vector_type(4)));
typedef float f32x4 __attribute__((ext_vector_type(4)));

#define GL2L(g, l)                                                                       \
  __builtin_amdgcn_global_load_lds((const __attribute__((address_space(1))) void*)(g),   \
                                   (__attribute__((address_space(3))) void*)(l), 16, 0, 0)

// ---------------- zero counters ----------------
__global__ void zero_counts_kernel(int* counts) {
  if (threadIdx.x < E_NUM) counts[threadIdx.x] = 0;
}

// ---------------- transpose + cast fp32 [Z,R,C] -> bf16 [Z,C,R] ----------------
__global__ void transpose_cast_kernel(const float* __restrict__ in, __bf16* __restrict__ out,
                                      int R, int C) {
  __shared__ float tile[32][33];
  int z = blockIdx.z;
  int c0 = blockIdx.x * 32, r0 = blockIdx.y * 32;
  const float* ip = in + (size_t)z * R * C;
  __bf16* op = out + (size_t)z * R * C;
  int tx = threadIdx.x, ty = threadIdx.y;  // 32 x 8
#pragma unroll
  for (int j = 0; j < 4; j++) tile[ty + 8 * j][tx] = ip[(size_t)(r0 + ty + 8 * j) * C + c0 + tx];
  __syncthreads();
#pragma unroll
  for (int j = 0; j < 4; j++)
    op[(size_t)(c0 + ty + 8 * j) * R + r0 + tx] = (__bf16)tile[tx][ty + 8 * j];
}

// ---------------- router: logits (fp32), softmax, top-4, cast x->bf16 ----------------
__global__ void router_kernel(const float* __restrict__ x, const float* __restrict__ gw,
                              const float* __restrict__ cbias, float* __restrict__ logits_out,
                              __bf16* __restrict__ x_bf, int* __restrict__ counts,
                              int* __restrict__ selE, float* __restrict__ selW) {
  int t = blockIdx.x;
  int lane = threadIdx.x;  // 64 threads
  const float* xr = x + (size_t)t * H_DIM;
  float xv[16];
#pragma unroll
  for (int i = 0; i < 16; i++) {
    float v = xr[lane + 64 * i];
    xv[i] = v;
    x_bf[(size_t)t * H_DIM + lane + 64 * i] = (__bf16)v;
  }
  __shared__ float lsm[E_NUM];
  for (int e = 0; e < E_NUM; e++) {
    float a = 0.f;
#pragma unroll
    for (int i = 0; i < 16; i++) a += xv[i] * gw[(lane + 64 * i) * E_NUM + e];
#pragma unroll
    for (int off = 32; off > 0; off >>= 1) a += __shfl_down(a, off);
    if (lane == 0) lsm[e] = a;
  }
  __syncthreads();
  if (lane < E_NUM) logits_out[(size_t)t * E_NUM + lane] = lsm[lane];
  if (lane == 0) {
    float probs[E_NUM];
    float m = -1e30f;
    for (int e = 0; e < E_NUM; e++) m = fmaxf(m, lsm[e]);
    float s = 0.f;
    for (int e = 0; e < E_NUM; e++) {
      probs[e] = __expf(lsm[e] - m);
      s += probs[e];
    }
    float inv = 1.f / s;
    float score[E_NUM];
    for (int e = 0; e < E_NUM; e++) {
      probs[e] *= inv;
      score[e] = probs[e] + cbias[e];
    }
    int sel[K_TOP];
    float w[K_TOP];
    bool taken[E_NUM] = {};
    for (int k = 0; k < K_TOP; k++) {
      int best = 0;
      float bv = -1e30f;
      for (int e = 0; e < E_NUM; e++)
        if (!taken[e] && score[e] > bv) {
          bv = score[e];
          best = e;
        }
      taken[best] = true;
      sel[k] = best;
      w[k] = probs[best];
    }
    float wsum = fmaxf(w[0] + w[1] + w[2] + w[3], 1e-12f);
    for (int k = 0; k < K_TOP; k++) {
      selE[t * K_TOP + k] = sel[k];
      selW[t * K_TOP + k] = w[k] / wsum;
      atomicAdd(&counts[sel[k]], 1);
    }
  }
}

// ---------------- prefix scan of counts ----------------
__global__ void scan_kernel(const int* __restrict__ counts, int* __restrict__ offs,
                            int* __restrict__ cursor) {
  if (threadIdx.x == 0) {
    int s = 0;
    for (int e = 0; e < E_NUM; e++) {
      offs[e] = s;
      cursor[e] = s;
      s += counts[e];
    }
    offs[E_NUM] = s;
  }
}

// ---------------- place tokens into per-expert contiguous slots ----------------
__global__ void place_kernel(const int* __restrict__ selE, int* cursor,
                             int* __restrict__ slot_of_tk, int* __restrict__ tok_of_slot) {
  int t = blockIdx.x * blockDim.x + threadIdx.x;
  if (t >= T_TOK) return;
  for (int k = 0; k < K_TOP; k++) {
    int e = selE[t * K_TOP + k];
    int pos = atomicAdd(&cursor[e], 1);
    slot_of_tk[t * K_TOP + k] = pos;
    tok_of_slot[pos] = t;
  }
}

// ---------------- bf16 MFMA GEMM, 128x128 tile, BK=32 (m97 structure) ----------------
// A rows: if tokIdx: A row = tokIdx[rowOff + r] (gather); else A row = rowOff + r.
// B is [N,K] row-major (pre-transposed weights), per-z offset z*strideB.
// C rows at (rowOff + r), stride N. If Bu != null, grid.x doubled: upper half uses Bu/Cu.
__global__ __launch_bounds__(256, 2) void gemm_bf16(
    const __bf16* __restrict__ A, const __bf16* __restrict__ B, const __bf16* __restrict__ Bu,
    __bf16* __restrict__ C, __bf16* __restrict__ Cu, const int* __restrict__ tokIdx,
    const int* __restrict__ cntPtr, const int* __restrict__ offPtr, size_t strideB, int Mfixed,
    int N, int K) {
  int z = blockIdx.z;
  int M = cntPtr ? cntPtr[z] : Mfixed;
  int m0 = blockIdx.y * 128;
  if (m0 >= M) return;
  const __bf16* Bp = B;
  __bf16* Cp = C;
  int nb = blockIdx.x;
  int NB = N >> 7;
  if (Bu && nb >= NB) {
    Bp = Bu;
    Cp = Cu;
    nb -= NB;
  }
  int n0 = nb << 7;
  int rowOff = offPtr ? offPtr[z] : 0;
  Bp += (size_t)z * strideB;

  __shared__ __align__(16) __bf16 Alds[128 * 32];
  __shared__ __align__(16) __bf16 Blds[128 * 32];

  int tid = threadIdx.x;
  int wave = tid >> 6, lane = tid & 63;
  // staging: wave w stages LDS chunks w and w+4 (each 1KB = 16 rows x 64B)
  int sRow0 = wave * 16 + (lane >> 2);
  int sRow1 = sRow0 + 64;
  int sCol = (lane & 3) * 8;  // bf16 elems within 64B row window

  auto aIdx = [&](int r) -> size_t {
    int rr = r < M - 1 ? r : M - 1;
    int rg = rowOff + rr;
    int ar = tokIdx ? tokIdx[rg] : rg;
    return (size_t)ar * K;
  };
  size_t aB0 = aIdx(m0 + sRow0) + sCol;
  size_t aB1 = aIdx(m0 + sRow1) + sCol;
  size_t bB0 = (size_t)(n0 + sRow0) * K + sCol;
  size_t bB1 = (size_t)(n0 + sRow1) * K + sCol;

  __bf16* ldsA0 = &Alds[wave * 512];
  __bf16* ldsA1 = &Alds[(wave + 4) * 512];
  __bf16* ldsB0 = &Blds[wave * 512];
  __bf16* ldsB1 = &Blds[(wave + 4) * 512];

  int wm = (wave >> 1) * 64, wn = (wave & 1) * 64;
  int rl = lane & 15, gq = lane >> 4;

  f32x4 acc[4][4] = {};

  for (int k0 = 0; k0 < K; k0 += 32) {
    GL2L(A + aB0 + k0, ldsA0);
    GL2L(A + aB1 + k0, ldsA1);
    GL2L(Bp + bB0 + k0, ldsB0);
    GL2L(Bp + bB1 + k0, ldsB1);
    __syncthreads();
    bf16x8 af[4], bfr[4];
#pragma unroll
    for (int m = 0; m < 4; m++) af[m] = *(const bf16x8*)&Alds[(wm + m * 16 + rl) * 32 + gq * 8];
#pragma unroll
    for (int n = 0; n < 4; n++) bfr[n] = *(const bf16x8*)&Blds[(wn + n * 16 + rl) * 32 + gq * 8];
#pragma unroll
    for (int m = 0; m < 4; m++)
#pragma unroll
      for (int n = 0; n < 4; n++)
        acc[m][n] = __builtin_amdgcn_mfma_f32_16x16x32_bf16(af[m], bfr[n], acc[m][n], 0, 0, 0);
    __syncthreads();
  }

#pragma unroll
  for (int m = 0; m < 4; m++) {
#pragma unroll
    for (int b = 0; b < 4; b++) {
      int row = m0 + wm + m * 16 + gq * 4 + b;
      if (row < M) {
        size_t rb = (size_t)(rowOff + row) * N + n0 + wn + rl;
#pragma unroll
        for (int n = 0; n < 4; n++) Cp[rb + n * 16] = (__bf16)acc[m][n][b];
      }
    }
  }
}

// ---------------- silu(g)*u elementwise ----------------
__global__ void silu_mul_kernel(const __bf16* __restrict__ g, const __bf16* __restrict__ u,
                                __bf16* __restrict__ h, long n8) {
  long i = blockIdx.x * (long)blockDim.x + threadIdx.x;
  if (i >= n8) return;
  bf16x8 gv = *(const bf16x8*)(g + i * 8);
  bf16x8 uv = *(const bf16x8*)(u + i * 8);
  bf16x8 hv;
#pragma unroll
  for (int j = 0; j < 8; j++) {
    float gf = (float)gv[j];
    float s = gf / (1.f + __expf(-gf));
    hv[j] = (__bf16)(s * (float)uv[j]);
  }
  *(bf16x8*)(h + i * 8) = hv;
}

// ---------------- combine: out = shared + sum_k w_k * eo[slot_k] ----------------
__global__ void combine_kernel(const __bf16* __restrict__ eo, const __bf16* __restrict__ so,
                               const int* __restrict__ slot_of_tk, const float* __restrict__ selW,
                               float* __restrict__ out) {
  int idx = blockIdx.x * blockDim.x + threadIdx.x;  // T*H/4 threads
  int t = idx >> 8;
  int h4 = (idx & 255) * 4;
  if (t >= T_TOK) return;
  bf16x4 sv = *(const bf16x4*)(so + (size_t)t * H_DIM + h4);
  float a0 = (float)sv[0], a1 = (float)sv[1], a2 = (float)sv[2], a3 = (float)sv[3];
#pragma unroll
  for (int k = 0; k < K_TOP; k++) {
    int slot = slot_of_tk[t * K_TOP + k];
    float w = selW[t * K_TOP + k];
    bf16x4 ev = *(const bf16x4*)(eo + (size_t)slot * H_DIM + h4);
    a0 += w * (float)ev[0];
    a1 += w * (float)ev[1];
    a2 += w * (float)ev[2];
    a3 += w * (float)ev[3];
  }
  *(float4*)(out + (size_t)t * H_DIM + h4) = make_float4(a0, a1, a2, a3);
}

extern "C" void kernel_launch(void* const* d_in, const int* in_sizes, int n_in, void* d_out,
                              int out_size, void* d_ws, size_t ws_size, hipStream_t stream) {
  const float* x = (const float*)d_in[0];
  const float* gate_weight = (const float*)d_in[1];
  const float* corr_bias = (const float*)d_in[2];
  const float* gate_w = (const float*)d_in[3];
  const float* up_w = (const float*)d_in[4];
  const float* down_w = (const float*)d_in[5];
  const float* sgw = (const float*)d_in[6];
  const float* suw = (const float*)d_in[7];
  const float* sdw = (const float*)d_in[8];
  float* out = (float*)d_out;
  float* logits_out = out + (size_t)T_TOK * H_DIM;

  char* wsb = (char*)d_ws;
  size_t o = 0;
  auto nxt = [&](size_t bytes) -> void* {
    void* p = wsb + o;
    o += (bytes + 1023) & ~(size_t)1023;
    return p;
  };
  __bf16* x_bf = (__bf16*)nxt((size_t)T_TOK * H_DIM * 2);
  __bf16* gw_t = (__bf16*)nxt((size_t)E_NUM * I_DIM * H_DIM * 2);  // [E, I, H]
  __bf16* uw_t = (__bf16*)nxt((size_t)E_NUM * I_DIM * H_DIM * 2);
  __bf16* dw_t = (__bf16*)nxt((size_t)E_NUM * H_DIM * I_DIM * 2);  // [E, H, I]
  __bf16* sgw_t = (__bf16*)nxt((size_t)SI_DIM * H_DIM * 2);        // [SI, H]
  __bf16* suw_t = (__bf16*)nxt((size_t)SI_DIM * H_DIM * 2);
  __bf16* sdw_t = (__bf16*)nxt((size_t)H_DIM * SI_DIM * 2);  // [H, SI]
  __bf16* g_buf = (__bf16*)nxt((size_t)T_TOK * K_TOP * I_DIM * 2);
  __bf16* u_buf = (__bf16*)nxt((size_t)T_TOK * K_TOP * I_DIM * 2);
  __bf16* he = (__bf16*)nxt((size_t)T_TOK * K_TOP * I_DIM * 2);
  __bf16* eo = (__bf16*)nxt((size_t)T_TOK * K_TOP * H_DIM * 2);
  __bf16* gs_buf = (__bf16*)nxt((size_t)T_TOK * SI_DIM * 2);
  __bf16* us_buf = (__bf16*)nxt((size_t)T_TOK * SI_DIM * 2);
  __bf16* hs = (__bf16*)nxt((size_t)T_TOK * SI_DIM * 2);
  __bf16* so = (__bf16*)nxt((size_t)T_TOK * H_DIM * 2);
  int* counts = (int*)nxt(64);
  int* offs = (int*)nxt(128);
  int* cursor = (int*)nxt(64);
  int* selE = (int*)nxt((size_t)T_TOK * K_TOP * 4);
  float* selW = (float*)nxt((size_t)T_TOK * K_TOP * 4);
  int* slot_of_tk = (int*)nxt((size_t)T_TOK * K_TOP * 4);
  int* tok_of_slot = (int*)nxt((size_t)T_TOK * K_TOP * 4);
  (void)ws_size;
  (void)in_sizes;
  (void)n_in;
  (void)out_size;

  dim3 tb(32, 8);
  // weight transpose-casts: fp32 [Z,R,C] -> bf16 [Z,C,R]
  transpose_cast_kernel<<<dim3(I_DIM / 32, H_DIM / 32, E_NUM), tb, 0, stream>>>(gate_w, gw_t,
                                                                                H_DIM, I_DIM);
  transpose_cast_kernel<<<dim3(I_DIM / 32, H_DIM / 32, E_NUM), tb, 0, stream>>>(up_w, uw_t, H_DIM,
                                                                                I_DIM);
  transpose_cast_kernel<<<dim3(H_DIM / 32, I_DIM / 32, E_NUM), tb, 0, stream>>>(down_w, dw_t,
                                                                                I_DIM, H_DIM);
  transpose_cast_kernel<<<dim3(SI_DIM / 32, H_DIM / 32, 1), tb, 0, stream>>>(sgw, sgw_t, H_DIM,
                                                                             SI_DIM);
  transpose_cast_kernel<<<dim3(SI_DIM / 32, H_DIM / 32, 1), tb, 0, stream>>>(suw, suw_t, H_DIM,
                                                                             SI_DIM);
  transpose_cast_kernel<<<dim3(H_DIM / 32, SI_DIM / 32, 1), tb, 0, stream>>>(sdw, sdw_t, SI_DIM,
                                                                             H_DIM);

  zero_counts_kernel<<<1, 64, 0, stream>>>(counts);
  router_kernel<<<T_TOK, 64, 0, stream>>>(x, gate_weight, corr_bias, logits_out, x_bf, counts,
                                          selE, selW);
  scan_kernel<<<1, 64, 0, stream>>>(counts, offs, cursor);
  place_kernel<<<T_TOK / 256, 256, 0, stream>>>(selE, cursor, slot_of_tk, tok_of_slot);

  // expert gate+up (merged launch), silu*mul, down
  gemm_bf16<<<dim3(8, 16, E_NUM), 256, 0, stream>>>(x_bf, gw_t, uw_t, g_buf, u_buf, tok_of_slot,
                                                    counts, offs, (size_t)I_DIM * H_DIM, 0, I_DIM,
                                                    H_DIM);
  silu_mul_kernel<<<(T_TOK * K_TOP * I_DIM / 8) / 256, 256, 0, stream>>>(
      g_buf, u_buf, he, (long)T_TOK * K_TOP * I_DIM / 8);
  gemm_bf16<<<dim3(8, 16, E_NUM), 256, 0, stream>>>(he, dw_t, nullptr, eo, nullptr, nullptr,
                                                    counts, offs, (size_t)H_DIM * I_DIM, 0, H_DIM,
                                                    I_DIM);

  // shared experts
  gemm_bf16<<<dim3(16, 16, 1), 256, 0, stream>>>(x_bf, sgw_t, suw_t, gs_buf, us_buf, nullptr,
                                                 nullptr, nullptr, 0, T_TOK, SI_DIM, H_DIM);
  silu_mul_kernel<<<(T_TOK * SI_DIM / 8) / 256, 256, 0, stream>>>(gs_buf, us_buf, hs,
                                                                  (long)T_TOK * SI_DIM / 8);
  gemm_bf16<<<dim3(8, 16, 1), 256, 0, stream>>>(hs, sdw_t, nullptr, so, nullptr, nullptr, nullptr,
                                                nullptr, 0, T_TOK, H_DIM, SI_DIM);

  combine_kernel<<<(T_TOK * H_DIM / 4) / 256, 256, 0, stream>>>(eo, so, slot_of_tk, selW, out);
}

// Round 2
// 308.174 us; speedup vs baseline: 1.0860x; 1.0860x over previous
//
#include <hip/hip_runtime.h>
#include <hip/hip_bf16.h>

#define T_TOK 2048
#define H_DIM 1024
#define E_NUM 16
#define I_DIM 512
#define K_TOP 4
#define SI_DIM 1024

typedef __bf16 bf16x8 __attribute__((ext_vector_type(8)));
typedef __bf16 bf16x4 __attribute__((ext_vector_type(4)));
typedef float f32x4 __attribute__((ext_vector_type(4)));

#define GL2L(g, l)                                                                       \
  __builtin_amdgcn_global_load_lds((const __attribute__((address_space(1))) void*)(g),   \
                                   (__attribute__((address_space(3))) void*)(l), 16, 0, 0)

// ---------------- zero counters ----------------
__global__ void zero_counts_kernel(int* counts) {
  if (threadIdx.x < E_NUM) counts[threadIdx.x] = 0;
}

// ---------------- transpose + cast fp32 [Z,R,C] -> bf16 [Z,C,R] ----------------
__global__ void transpose_cast_kernel(const float* __restrict__ in, __bf16* __restrict__ out,
                                      int R, int C) {
  __shared__ float tile[32][33];
  int z = blockIdx.z;
  int c0 = blockIdx.x * 32, r0 = blockIdx.y * 32;
  const float* ip = in + (size_t)z * R * C;
  __bf16* op = out + (size_t)z * R * C;
  int tx = threadIdx.x, ty = threadIdx.y;  // 32 x 8
#pragma unroll
  for (int j = 0; j < 4; j++) tile[ty + 8 * j][tx] = ip[(size_t)(r0 + ty + 8 * j) * C + c0 + tx];
  __syncthreads();
#pragma unroll
  for (int j = 0; j < 4; j++)
    op[(size_t)(c0 + ty + 8 * j) * R + r0 + tx] = (__bf16)tile[tx][ty + 8 * j];
}

// ---------------- cast fp32 -> bf16, vectorized ----------------
__global__ void cast_bf16_kernel(const float* __restrict__ in, __bf16* __restrict__ out, long n8) {
  long i = blockIdx.x * (long)blockDim.x + threadIdx.x;
  if (i >= n8) return;
  float4 v0 = *(const float4*)(in + i * 8);
  float4 v1 = *(const float4*)(in + i * 8 + 4);
  bf16x8 o;
  o[0] = (__bf16)v0.x;
  o[1] = (__bf16)v0.y;
  o[2] = (__bf16)v0.z;
  o[3] = (__bf16)v0.w;
  o[4] = (__bf16)v1.x;
  o[5] = (__bf16)v1.y;
  o[6] = (__bf16)v1.z;
  o[7] = (__bf16)v1.w;
  *(bf16x8*)(out + i * 8) = o;
}

// ---------------- router: one wave per token, fully lane-parallel ----------------
// lane = e*4 + c : expert e (0..15), H-chunk c (0..3, 256 elems each)
__global__ __launch_bounds__(256) void router_kernel(
    const float* __restrict__ x, const float* __restrict__ gw, const float* __restrict__ cbias,
    float* __restrict__ logits_out, int* __restrict__ counts, int* __restrict__ selE,
    float* __restrict__ selW) {
  int wid = threadIdx.x >> 6;
  int t = blockIdx.x * 4 + wid;
  if (t >= T_TOK) return;
  int lane = threadIdx.x & 63;
  int e = lane >> 2, c = lane & 3;
  const float* xr = x + (size_t)t * H_DIM + c * 256;
  float a = 0.f;
#pragma unroll
  for (int j = 0; j < 64; j++) {
    float4 xv = *(const float4*)(xr + j * 4);
    const float* g0 = gw + (size_t)(c * 256 + j * 4) * E_NUM + e;
    a = fmaf(xv.x, g0[0], a);
    a = fmaf(xv.y, g0[E_NUM], a);
    a = fmaf(xv.z, g0[2 * E_NUM], a);
    a = fmaf(xv.w, g0[3 * E_NUM], a);
  }
  // reduce the 4 chunk-partials of each expert
  a += __shfl_xor(a, 1);
  a += __shfl_xor(a, 2);
  // lane e*4 holds logit[e]; replicate logits onto lanes 0..15 (mod 16)
  float logit = __shfl(a, (lane & 15) * 4);
  if (lane < E_NUM) logits_out[(size_t)t * E_NUM + lane] = logit;
  // softmax across the 16-lane group
  float m = logit;
#pragma unroll
  for (int mk = 8; mk >= 1; mk >>= 1) m = fmaxf(m, __shfl_xor(m, mk));
  float p = __expf(logit - m);
  float s = p;
#pragma unroll
  for (int mk = 8; mk >= 1; mk >>= 1) s += __shfl_xor(s, mk);
  p /= s;
  float score = (lane < E_NUM) ? p + cbias[lane] : -1e30f;
  int sel[K_TOP];
  float w[K_TOP];
#pragma unroll
  for (int k = 0; k < K_TOP; k++) {
    float bv = score;
    int bi = (lane < E_NUM) ? lane : 999;
#pragma unroll
    for (int mk = 1; mk <= 8; mk <<= 1) {
      float ov = __shfl_xor(bv, mk);
      int oi = __shfl_xor(bi, mk);
      if (ov > bv || (ov == bv && oi < bi)) {
        bv = ov;
        bi = oi;
      }
    }
    sel[k] = bi;
    w[k] = __shfl(p, bi);  // prob of chosen expert (lane bi holds it)
    if (lane == bi) score = -1e30f;
  }
  if (lane == 0) {
    float wsum = fmaxf(w[0] + w[1] + w[2] + w[3], 1e-12f);
#pragma unroll
    for (int k = 0; k < K_TOP; k++) {
      selE[t * K_TOP + k] = sel[k];
      selW[t * K_TOP + k] = w[k] / wsum;
      atomicAdd(&counts[sel[k]], 1);
    }
  }
}

// ---------------- prefix scan of counts ----------------
__global__ void scan_kernel(const int* __restrict__ counts, int* __restrict__ offs,
                            int* __restrict__ cursor) {
  if (threadIdx.x == 0) {
    int s = 0;
    for (int e = 0; e < E_NUM; e++) {
      offs[e] = s;
      cursor[e] = s;
      s += counts[e];
    }
    offs[E_NUM] = s;
  }
}

// ---------------- place tokens into per-expert contiguous slots ----------------
__global__ void place_kernel(const int* __restrict__ selE, int* cursor,
                             int* __restrict__ slot_of_tk, int* __restrict__ tok_of_slot) {
  int t = blockIdx.x * blockDim.x + threadIdx.x;
  if (t >= T_TOK) return;
  for (int k = 0; k < K_TOP; k++) {
    int e = selE[t * K_TOP + k];
    int pos = atomicAdd(&cursor[e], 1);
    slot_of_tk[t * K_TOP + k] = pos;
    tok_of_slot[pos] = t;
  }
}

// ---------------- bf16 MFMA GEMM, 128x128 tile, BK=32 (m97 structure) ----------------
// A rows: if tokIdx: A row = tokIdx[rowOff + r] (gather); else A row = rowOff + r.
// B is [N,K] row-major (pre-transposed weights), per-z offset z*strideB.
// C rows at (rowOff + r), stride N. If Bu != null, grid.x doubled: upper half uses Bu/Cu.
__global__ __launch_bounds__(256, 2) void gemm_bf16(
    const __bf16* __restrict__ A, const __bf16* __restrict__ B, const __bf16* __restrict__ Bu,
    __bf16* __restrict__ C, __bf16* __restrict__ Cu, const int* __restrict__ tokIdx,
    const int* __restrict__ cntPtr, const int* __restrict__ offPtr, size_t strideB, int Mfixed,
    int N, int K) {
  int z = blockIdx.z;
  int M = cntPtr ? cntPtr[z] : Mfixed;
  int m0 = blockIdx.y * 128;
  if (m0 >= M) return;
  const __bf16* Bp = B;
  __bf16* Cp = C;
  int nb = blockIdx.x;
  int NB = N >> 7;
  if (Bu && nb >= NB) {
    Bp = Bu;
    Cp = Cu;
    nb -= NB;
  }
  int n0 = nb << 7;
  int rowOff = offPtr ? offPtr[z] : 0;
  Bp += (size_t)z * strideB;

  __shared__ __align__(16) __bf16 Alds[128 * 32];
  __shared__ __align__(16) __bf16 Blds[128 * 32];

  int tid = threadIdx.x;
  int wave = tid >> 6, lane = tid & 63;
  // staging: wave w stages LDS chunks w and w+4 (each 1KB = 16 rows x 64B)
  int sRow0 = wave * 16 + (lane >> 2);
  int sRow1 = sRow0 + 64;
  int sCol = (lane & 3) * 8;  // bf16 elems within 64B row window

  auto aIdx = [&](int r) -> size_t {
    int rr = r < M - 1 ? r : M - 1;
    int rg = rowOff + rr;
    int ar = tokIdx ? tokIdx[rg] : rg;
    return (size_t)ar * K;
  };
  size_t aB0 = aIdx(m0 + sRow0) + sCol;
  size_t aB1 = aIdx(m0 + sRow1) + sCol;
  size_t bB0 = (size_t)(n0 + sRow0) * K + sCol;
  size_t bB1 = (size_t)(n0 + sRow1) * K + sCol;

  __bf16* ldsA0 = &Alds[wave * 512];
  __bf16* ldsA1 = &Alds[(wave + 4) * 512];
  __bf16* ldsB0 = &Blds[wave * 512];
  __bf16* ldsB1 = &Blds[(wave + 4) * 512];

  int wm = (wave >> 1) * 64, wn = (wave & 1) * 64;
  int rl = lane & 15, gq = lane >> 4;

  f32x4 acc[4][4] = {};

  for (int k0 = 0; k0 < K; k0 += 32) {
    GL2L(A + aB0 + k0, ldsA0);
    GL2L(A + aB1 + k0, ldsA1);
    GL2L(Bp + bB0 + k0, ldsB0);
    GL2L(Bp + bB1 + k0, ldsB1);
    __syncthreads();
    bf16x8 af[4], bfr[4];
#pragma unroll
    for (int m = 0; m < 4; m++) af[m] = *(const bf16x8*)&Alds[(wm + m * 16 + rl) * 32 + gq * 8];
#pragma unroll
    for (int n = 0; n < 4; n++) bfr[n] = *(const bf16x8*)&Blds[(wn + n * 16 + rl) * 32 + gq * 8];
#pragma unroll
    for (int m = 0; m < 4; m++)
#pragma unroll
      for (int n = 0; n < 4; n++)
        acc[m][n] = __builtin_amdgcn_mfma_f32_16x16x32_bf16(af[m], bfr[n], acc[m][n], 0, 0, 0);
    __syncthreads();
  }

#pragma unroll
  for (int m = 0; m < 4; m++) {
#pragma unroll
    for (int b = 0; b < 4; b++) {
      int row = m0 + wm + m * 16 + gq * 4 + b;
      if (row < M) {
        size_t rb = (size_t)(rowOff + row) * N + n0 + wn + rl;
#pragma unroll
        for (int n = 0; n < 4; n++) Cp[rb + n * 16] = (__bf16)acc[m][n][b];
      }
    }
  }
}

// ---------------- silu(g)*u elementwise ----------------
__global__ void silu_mul_kernel(const __bf16* __restrict__ g, const __bf16* __restrict__ u,
                                __bf16* __restrict__ h, long n8) {
  long i = blockIdx.x * (long)blockDim.x + threadIdx.x;
  if (i >= n8) return;
  bf16x8 gv = *(const bf16x8*)(g + i * 8);
  bf16x8 uv = *(const bf16x8*)(u + i * 8);
  bf16x8 hv;
#pragma unroll
  for (int j = 0; j < 8; j++) {
    float gf = (float)gv[j];
    float s = gf / (1.f + __expf(-gf));
    hv[j] = (__bf16)(s * (float)uv[j]);
  }
  *(bf16x8*)(h + i * 8) = hv;
}

// ---------------- combine: out = shared + sum_k w_k * eo[slot_k] ----------------
__global__ void combine_kernel(const __bf16* __restrict__ eo, const __bf16* __restrict__ so,
                               const int* __restrict__ slot_of_tk, const float* __restrict__ selW,
                               float* __restrict__ out) {
  int idx = blockIdx.x * blockDim.x + threadIdx.x;  // T*H/4 threads
  int t = idx >> 8;
  int h4 = (idx & 255) * 4;
  if (t >= T_TOK) return;
  bf16x4 sv = *(const bf16x4*)(so + (size_t)t * H_DIM + h4);
  float a0 = (float)sv[0], a1 = (float)sv[1], a2 = (float)sv[2], a3 = (float)sv[3];
#pragma unroll
  for (int k = 0; k < K_TOP; k++) {
    int slot = slot_of_tk[t * K_TOP + k];
    float w = selW[t * K_TOP + k];
    bf16x4 ev = *(const bf16x4*)(eo + (size_t)slot * H_DIM + h4);
    a0 += w * (float)ev[0];
    a1 += w * (float)ev[1];
    a2 += w * (float)ev[2];
    a3 += w * (float)ev[3];
  }
  *(float4*)(out + (size_t)t * H_DIM + h4) = make_float4(a0, a1, a2, a3);
}

extern "C" void kernel_launch(void* const* d_in, const int* in_sizes, int n_in, void* d_out,
                              int out_size, void* d_ws, size_t ws_size, hipStream_t stream) {
  const float* x = (const float*)d_in[0];
  const float* gate_weight = (const float*)d_in[1];
  const float* corr_bias = (const float*)d_in[2];
  const float* gate_w = (const float*)d_in[3];
  const float* up_w = (const float*)d_in[4];
  const float* down_w = (const float*)d_in[5];
  const float* sgw = (const float*)d_in[6];
  const float* suw = (const float*)d_in[7];
  const float* sdw = (const float*)d_in[8];
  float* out = (float*)d_out;
  float* logits_out = out + (size_t)T_TOK * H_DIM;

  char* wsb = (char*)d_ws;
  size_t o = 0;
  auto nxt = [&](size_t bytes) -> void* {
    void* p = wsb + o;
    o += (bytes + 1023) & ~(size_t)1023;
    return p;
  };
  __bf16* x_bf = (__bf16*)nxt((size_t)T_TOK * H_DIM * 2);
  __bf16* gw_t = (__bf16*)nxt((size_t)E_NUM * I_DIM * H_DIM * 2);  // [E, I, H]
  __bf16* uw_t = (__bf16*)nxt((size_t)E_NUM * I_DIM * H_DIM * 2);
  __bf16* dw_t = (__bf16*)nxt((size_t)E_NUM * H_DIM * I_DIM * 2);  // [E, H, I]
  __bf16* sgw_t = (__bf16*)nxt((size_t)SI_DIM * H_DIM * 2);        // [SI, H]
  __bf16* suw_t = (__bf16*)nxt((size_t)SI_DIM * H_DIM * 2);
  __bf16* sdw_t = (__bf16*)nxt((size_t)H_DIM * SI_DIM * 2);  // [H, SI]
  __bf16* g_buf = (__bf16*)nxt((size_t)T_TOK * K_TOP * I_DIM * 2);
  __bf16* u_buf = (__bf16*)nxt((size_t)T_TOK * K_TOP * I_DIM * 2);
  __bf16* he = (__bf16*)nxt((size_t)T_TOK * K_TOP * I_DIM * 2);
  __bf16* eo = (__bf16*)nxt((size_t)T_TOK * K_TOP * H_DIM * 2);
  __bf16* gs_buf = (__bf16*)nxt((size_t)T_TOK * SI_DIM * 2);
  __bf16* us_buf = (__bf16*)nxt((size_t)T_TOK * SI_DIM * 2);
  __bf16* hs = (__bf16*)nxt((size_t)T_TOK * SI_DIM * 2);
  __bf16* so = (__bf16*)nxt((size_t)T_TOK * H_DIM * 2);
  int* counts = (int*)nxt(64);
  int* offs = (int*)nxt(128);
  int* cursor = (int*)nxt(64);
  int* selE = (int*)nxt((size_t)T_TOK * K_TOP * 4);
  float* selW = (float*)nxt((size_t)T_TOK * K_TOP * 4);
  int* slot_of_tk = (int*)nxt((size_t)T_TOK * K_TOP * 4);
  int* tok_of_slot = (int*)nxt((size_t)T_TOK * K_TOP * 4);
  (void)ws_size;
  (void)in_sizes;
  (void)n_in;
  (void)out_size;

  dim3 tb(32, 8);
  // weight transpose-casts: fp32 [Z,R,C] -> bf16 [Z,C,R]
  transpose_cast_kernel<<<dim3(I_DIM / 32, H_DIM / 32, E_NUM), tb, 0, stream>>>(gate_w, gw_t,
                                                                                H_DIM, I_DIM);
  transpose_cast_kernel<<<dim3(I_DIM / 32, H_DIM / 32, E_NUM), tb, 0, stream>>>(up_w, uw_t, H_DIM,
                                                                                I_DIM);
  transpose_cast_kernel<<<dim3(H_DIM / 32, I_DIM / 32, E_NUM), tb, 0, stream>>>(down_w, dw_t,
                                                                                I_DIM, H_DIM);
  transpose_cast_kernel<<<dim3(SI_DIM / 32, H_DIM / 32, 1), tb, 0, stream>>>(sgw, sgw_t, H_DIM,
                                                                             SI_DIM);
  transpose_cast_kernel<<<dim3(SI_DIM / 32, H_DIM / 32, 1), tb, 0, stream>>>(suw, suw_t, H_DIM,
                                                                             SI_DIM);
  transpose_cast_kernel<<<dim3(H_DIM / 32, SI_DIM / 32, 1), tb, 0, stream>>>(sdw, sdw_t, SI_DIM,
                                                                             H_DIM);

  cast_bf16_kernel<<<(T_TOK * H_DIM / 8) / 256, 256, 0, stream>>>(x, x_bf,
                                                                  (long)T_TOK * H_DIM / 8);
  zero_counts_kernel<<<1, 64, 0, stream>>>(counts);
  router_kernel<<<T_TOK / 4, 256, 0, stream>>>(x, gate_weight, corr_bias, logits_out, counts,
                                               selE, selW);
  scan_kernel<<<1, 64, 0, stream>>>(counts, offs, cursor);
  place_kernel<<<T_TOK / 256, 256, 0, stream>>>(selE, cursor, slot_of_tk, tok_of_slot);

  // expert gate+up (merged launch), silu*mul, down
  gemm_bf16<<<dim3(8, 16, E_NUM), 256, 0, stream>>>(x_bf, gw_t, uw_t, g_buf, u_buf, tok_of_slot,
                                                    counts, offs, (size_t)I_DIM * H_DIM, 0, I_DIM,
                                                    H_DIM);
  silu_mul_kernel<<<(T_TOK * K_TOP * I_DIM / 8) / 256, 256, 0, stream>>>(
      g_buf, u_buf, he, (long)T_TOK * K_TOP * I_DIM / 8);
  gemm_bf16<<<dim3(8, 16, E_NUM), 256, 0, stream>>>(he, dw_t, nullptr, eo, nullptr, nullptr,
                                                    counts, offs, (size_t)H_DIM * I_DIM, 0, H_DIM,
                                                    I_DIM);

  // shared experts
  gemm_bf16<<<dim3(16, 16, 1), 256, 0, stream>>>(x_bf, sgw_t, suw_t, gs_buf, us_buf, nullptr,
                                                 nullptr, nullptr, 0, T_TOK, SI_DIM, H_DIM);
  silu_mul_kernel<<<(T_TOK * SI_DIM / 8) / 256, 256, 0, stream>>>(gs_buf, us_buf, hs,
                                                                  (long)T_TOK * SI_DIM / 8);
  gemm_bf16<<<dim3(8, 16, 1), 256, 0, stream>>>(hs, sdw_t, nullptr, so, nullptr, nullptr, nullptr,
                                                nullptr, 0, T_TOK, H_DIM, SI_DIM);

  combine_kernel<<<(T_TOK * H_DIM / 4) / 256, 256, 0, stream>>>(eo, so, slot_of_tk, selW, out);
}

// Round 3
// 303.888 us; speedup vs baseline: 1.1014x; 1.0141x over previous
//
#include <hip/hip_runtime.h>
#include <hip/hip_bf16.h>

#define T_TOK 2048
#define H_DIM 1024
#define E_NUM 16
#define I_DIM 512
#define K_TOP 4
#define SI_DIM 1024

typedef __bf16 bf16x8 __attribute__((ext_vector_type(8)));
typedef __bf16 bf16x4 __attribute__((ext_vector_type(4)));
typedef float f32x4 __attribute__((ext_vector_type(4)));

#define GL2L(g, l)                                                                       \
  __builtin_amdgcn_global_load_lds((const __attribute__((address_space(1))) void*)(g),   \
                                   (__attribute__((address_space(3))) void*)(l), 16, 0, 0)

// ---------------- zero counters ----------------
__global__ void zero_counts_kernel(int* counts) {
  if (threadIdx.x < E_NUM) counts[threadIdx.x] = 0;
}

// ---------------- transpose gate_weight [H,E] -> [E,H] (tiny) ----------------
__global__ void transpose_gw_kernel(const float* __restrict__ in, float* __restrict__ out) {
  int idx = blockIdx.x * 256 + threadIdx.x;  // 16384
  int e = idx >> 10, h = idx & 1023;
  out[idx] = in[h * E_NUM + e];
}

// ---------------- transpose + cast fp32 [Z,R,C] -> bf16 [Z,C,R] ----------------
__global__ void transpose_cast_kernel(const float* __restrict__ in, __bf16* __restrict__ out,
                                      int R, int C) {
  __shared__ float tile[32][33];
  int z = blockIdx.z;
  int c0 = blockIdx.x * 32, r0 = blockIdx.y * 32;
  const float* ip = in + (size_t)z * R * C;
  __bf16* op = out + (size_t)z * R * C;
  int tx = threadIdx.x, ty = threadIdx.y;  // 32 x 8
#pragma unroll
  for (int j = 0; j < 4; j++) tile[ty + 8 * j][tx] = ip[(size_t)(r0 + ty + 8 * j) * C + c0 + tx];
  __syncthreads();
#pragma unroll
  for (int j = 0; j < 4; j++)
    op[(size_t)(c0 + ty + 8 * j) * R + r0 + tx] = (__bf16)tile[tx][ty + 8 * j];
}

// ---------------- cast fp32 -> bf16, vectorized ----------------
__global__ void cast_bf16_kernel(const float* __restrict__ in, __bf16* __restrict__ out, long n8) {
  long i = blockIdx.x * (long)blockDim.x + threadIdx.x;
  if (i >= n8) return;
  float4 v0 = *(const float4*)(in + i * 8);
  float4 v1 = *(const float4*)(in + i * 8 + 4);
  bf16x8 o;
  o[0] = (__bf16)v0.x;
  o[1] = (__bf16)v0.y;
  o[2] = (__bf16)v0.z;
  o[3] = (__bf16)v0.w;
  o[4] = (__bf16)v1.x;
  o[5] = (__bf16)v1.y;
  o[6] = (__bf16)v1.z;
  o[7] = (__bf16)v1.w;
  *(bf16x8*)(out + i * 8) = o;
}

// ---------------- router: one block (4 waves) per token ----------------
// thread -> (expert e = lane>>2, chunk c = wid*4 + (lane&3)); 64-elem dot each
__global__ __launch_bounds__(256) void router_kernel(
    const float* __restrict__ x, const float* __restrict__ gwt, const float* __restrict__ cbias,
    float* __restrict__ logits_out, int* __restrict__ counts, int* __restrict__ selE,
    float* __restrict__ selW) {
  int t = blockIdx.x;
  int tid = threadIdx.x;
  int wid = tid >> 6, lane = tid & 63;
  int e = lane >> 2, cl = lane & 3;
  int c = wid * 4 + cl;  // 0..15
  const float* xr = x + (size_t)t * H_DIM + c * 64;
  const float* gr = gwt + (size_t)e * H_DIM + c * 64;
  float a0 = 0.f, a1 = 0.f, a2 = 0.f, a3 = 0.f;
#pragma unroll
  for (int j = 0; j < 16; j++) {
    float4 xv = *(const float4*)(xr + j * 4);
    float4 gv = *(const float4*)(gr + j * 4);
    a0 = fmaf(xv.x, gv.x, a0);
    a1 = fmaf(xv.y, gv.y, a1);
    a2 = fmaf(xv.z, gv.z, a2);
    a3 = fmaf(xv.w, gv.w, a3);
  }
  float a = (a0 + a1) + (a2 + a3);
  // reduce 4 chunk-partials within wave (lanes differ in cl)
  a += __shfl_xor(a, 1);
  a += __shfl_xor(a, 2);
  __shared__ float part[4][16];
  if (cl == 0) part[wid][e] = a;
  __syncthreads();
  if (wid != 0) return;
  // wave 0, lanes 0..15 hold the 16 logits
  float logit = -1e30f;
  if (lane < E_NUM)
    logit = (part[0][lane] + part[1][lane]) + (part[2][lane] + part[3][lane]);
  if (lane < E_NUM) logits_out[(size_t)t * E_NUM + lane] = logit;
  // softmax across the 16-lane group
  float m = logit;
#pragma unroll
  for (int mk = 8; mk >= 1; mk >>= 1) m = fmaxf(m, __shfl_xor(m, mk));
  float p = __expf(logit - m);
  float s = p;
#pragma unroll
  for (int mk = 8; mk >= 1; mk >>= 1) s += __shfl_xor(s, mk);
  p /= s;
  float score = (lane < E_NUM) ? p + cbias[lane] : -1e30f;
  int sel[K_TOP];
  float w[K_TOP];
#pragma unroll
  for (int k = 0; k < K_TOP; k++) {
    float bv = score;
    int bi = (lane < E_NUM) ? lane : 999;
#pragma unroll
    for (int mk = 1; mk <= 8; mk <<= 1) {
      float ov = __shfl_xor(bv, mk);
      int oi = __shfl_xor(bi, mk);
      if (ov > bv || (ov == bv && oi < bi)) {
        bv = ov;
        bi = oi;
      }
    }
    sel[k] = bi;
    w[k] = __shfl(p, bi);
    if (lane == bi) score = -1e30f;
  }
  if (lane == 0) {
    float wsum = fmaxf(w[0] + w[1] + w[2] + w[3], 1e-12f);
#pragma unroll
    for (int k = 0; k < K_TOP; k++) {
      selE[t * K_TOP + k] = sel[k];
      selW[t * K_TOP + k] = w[k] / wsum;
      atomicAdd(&counts[sel[k]], 1);
    }
  }
}

// ---------------- prefix scan of counts ----------------
__global__ void scan_kernel(const int* __restrict__ counts, int* __restrict__ offs,
                            int* __restrict__ cursor) {
  if (threadIdx.x == 0) {
    int s = 0;
    for (int e = 0; e < E_NUM; e++) {
      offs[e] = s;
      cursor[e] = s;
      s += counts[e];
    }
    offs[E_NUM] = s;
  }
}

// ---------------- place tokens into per-expert contiguous slots ----------------
__global__ void place_kernel(const int* __restrict__ selE, int* cursor,
                             int* __restrict__ slot_of_tk, int* __restrict__ tok_of_slot) {
  int t = blockIdx.x * blockDim.x + threadIdx.x;
  if (t >= T_TOK) return;
  for (int k = 0; k < K_TOP; k++) {
    int e = selE[t * K_TOP + k];
    int pos = atomicAdd(&cursor[e], 1);
    slot_of_tk[t * K_TOP + k] = pos;
    tok_of_slot[pos] = t;
  }
}

// ---------------- bf16 MFMA GEMM, 128x128 tile, BK=32 (m97 structure) ----------------
__global__ __launch_bounds__(256, 2) void gemm_bf16(
    const __bf16* __restrict__ A, const __bf16* __restrict__ B, const __bf16* __restrict__ Bu,
    __bf16* __restrict__ C, __bf16* __restrict__ Cu, const int* __restrict__ tokIdx,
    const int* __restrict__ cntPtr, const int* __restrict__ offPtr, size_t strideB, int Mfixed,
    int N, int K) {
  int z = blockIdx.z;
  int M = cntPtr ? cntPtr[z] : Mfixed;
  int m0 = blockIdx.y * 128;
  if (m0 >= M) return;
  const __bf16* Bp = B;
  __bf16* Cp = C;
  int nb = blockIdx.x;
  int NB = N >> 7;
  if (Bu && nb >= NB) {
    Bp = Bu;
    Cp = Cu;
    nb -= NB;
  }
  int n0 = nb << 7;
  int rowOff = offPtr ? offPtr[z] : 0;
  Bp += (size_t)z * strideB;

  __shared__ __align__(16) __bf16 Alds[128 * 32];
  __shared__ __align__(16) __bf16 Blds[128 * 32];

  int tid = threadIdx.x;
  int wave = tid >> 6, lane = tid & 63;
  int sRow0 = wave * 16 + (lane >> 2);
  int sRow1 = sRow0 + 64;
  int sCol = (lane & 3) * 8;

  auto aIdx = [&](int r) -> size_t {
    int rr = r < M - 1 ? r : M - 1;
    int rg = rowOff + rr;
    int ar = tokIdx ? tokIdx[rg] : rg;
    return (size_t)ar * K;
  };
  size_t aB0 = aIdx(m0 + sRow0) + sCol;
  size_t aB1 = aIdx(m0 + sRow1) + sCol;
  size_t bB0 = (size_t)(n0 + sRow0) * K + sCol;
  size_t bB1 = (size_t)(n0 + sRow1) * K + sCol;

  __bf16* ldsA0 = &Alds[wave * 512];
  __bf16* ldsA1 = &Alds[(wave + 4) * 512];
  __bf16* ldsB0 = &Blds[wave * 512];
  __bf16* ldsB1 = &Blds[(wave + 4) * 512];

  int wm = (wave >> 1) * 64, wn = (wave & 1) * 64;
  int rl = lane & 15, gq = lane >> 4;

  f32x4 acc[4][4] = {};

  for (int k0 = 0; k0 < K; k0 += 32) {
    GL2L(A + aB0 + k0, ldsA0);
    GL2L(A + aB1 + k0, ldsA1);
    GL2L(Bp + bB0 + k0, ldsB0);
    GL2L(Bp + bB1 + k0, ldsB1);
    __syncthreads();
    bf16x8 af[4], bfr[4];
#pragma unroll
    for (int m = 0; m < 4; m++) af[m] = *(const bf16x8*)&Alds[(wm + m * 16 + rl) * 32 + gq * 8];
#pragma unroll
    for (int n = 0; n < 4; n++) bfr[n] = *(const bf16x8*)&Blds[(wn + n * 16 + rl) * 32 + gq * 8];
#pragma unroll
    for (int m = 0; m < 4; m++)
#pragma unroll
      for (int n = 0; n < 4; n++)
        acc[m][n] = __builtin_amdgcn_mfma_f32_16x16x32_bf16(af[m], bfr[n], acc[m][n], 0, 0, 0);
    __syncthreads();
  }

#pragma unroll
  for (int m = 0; m < 4; m++) {
#pragma unroll
    for (int b = 0; b < 4; b++) {
      int row = m0 + wm + m * 16 + gq * 4 + b;
      if (row < M) {
        size_t rb = (size_t)(rowOff + row) * N + n0 + wn + rl;
#pragma unroll
        for (int n = 0; n < 4; n++) Cp[rb + n * 16] = (__bf16)acc[m][n][b];
      }
    }
  }
}

// ---------------- silu(g)*u elementwise ----------------
__global__ void silu_mul_kernel(const __bf16* __restrict__ g, const __bf16* __restrict__ u,
                                __bf16* __restrict__ h, long n8) {
  long i = blockIdx.x * (long)blockDim.x + threadIdx.x;
  if (i >= n8) return;
  bf16x8 gv = *(const bf16x8*)(g + i * 8);
  bf16x8 uv = *(const bf16x8*)(u + i * 8);
  bf16x8 hv;
#pragma unroll
  for (int j = 0; j < 8; j++) {
    float gf = (float)gv[j];
    float s = gf / (1.f + __expf(-gf));
    hv[j] = (__bf16)(s * (float)uv[j]);
  }
  *(bf16x8*)(h + i * 8) = hv;
}

// ---------------- combine: out = shared + sum_k w_k * eo[slot_k] ----------------
__global__ void combine_kernel(const __bf16* __restrict__ eo, const __bf16* __restrict__ so,
                               const int* __restrict__ slot_of_tk, const float* __restrict__ selW,
                               float* __restrict__ out) {
  int idx = blockIdx.x * blockDim.x + threadIdx.x;
  int t = idx >> 8;
  int h4 = (idx & 255) * 4;
  if (t >= T_TOK) return;
  bf16x4 sv = *(const bf16x4*)(so + (size_t)t * H_DIM + h4);
  float a0 = (float)sv[0], a1 = (float)sv[1], a2 = (float)sv[2], a3 = (float)sv[3];
#pragma unroll
  for (int k = 0; k < K_TOP; k++) {
    int slot = slot_of_tk[t * K_TOP + k];
    float w = selW[t * K_TOP + k];
    bf16x4 ev = *(const bf16x4*)(eo + (size_t)slot * H_DIM + h4);
    a0 += w * (float)ev[0];
    a1 += w * (float)ev[1];
    a2 += w * (float)ev[2];
    a3 += w * (float)ev[3];
  }
  *(float4*)(out + (size_t)t * H_DIM + h4) = make_float4(a0, a1, a2, a3);
}

extern "C" void kernel_launch(void* const* d_in, const int* in_sizes, int n_in, void* d_out,
                              int out_size, void* d_ws, size_t ws_size, hipStream_t stream) {
  const float* x = (const float*)d_in[0];
  const float* gate_weight = (const float*)d_in[1];
  const float* corr_bias = (const float*)d_in[2];
  const float* gate_w = (const float*)d_in[3];
  const float* up_w = (const float*)d_in[4];
  const float* down_w = (const float*)d_in[5];
  const float* sgw = (const float*)d_in[6];
  const float* suw = (const float*)d_in[7];
  const float* sdw = (const float*)d_in[8];
  float* out = (float*)d_out;
  float* logits_out = out + (size_t)T_TOK * H_DIM;

  char* wsb = (char*)d_ws;
  size_t o = 0;
  auto nxt = [&](size_t bytes) -> void* {
    void* p = wsb + o;
    o += (bytes + 1023) & ~(size_t)1023;
    return p;
  };
  __bf16* x_bf = (__bf16*)nxt((size_t)T_TOK * H_DIM * 2);
  __bf16* gw_t = (__bf16*)nxt((size_t)E_NUM * I_DIM * H_DIM * 2);  // [E, I, H]
  __bf16* uw_t = (__bf16*)nxt((size_t)E_NUM * I_DIM * H_DIM * 2);
  __bf16* dw_t = (__bf16*)nxt((size_t)E_NUM * H_DIM * I_DIM * 2);  // [E, H, I]
  __bf16* sgw_t = (__bf16*)nxt((size_t)SI_DIM * H_DIM * 2);        // [SI, H]
  __bf16* suw_t = (__bf16*)nxt((size_t)SI_DIM * H_DIM * 2);
  __bf16* sdw_t = (__bf16*)nxt((size_t)H_DIM * SI_DIM * 2);  // [H, SI]
  __bf16* g_buf = (__bf16*)nxt((size_t)T_TOK * K_TOP * I_DIM * 2);
  __bf16* u_buf = (__bf16*)nxt((size_t)T_TOK * K_TOP * I_DIM * 2);
  __bf16* he = (__bf16*)nxt((size_t)T_TOK * K_TOP * I_DIM * 2);
  __bf16* eo = (__bf16*)nxt((size_t)T_TOK * K_TOP * H_DIM * 2);
  __bf16* gs_buf = (__bf16*)nxt((size_t)T_TOK * SI_DIM * 2);
  __bf16* us_buf = (__bf16*)nxt((size_t)T_TOK * SI_DIM * 2);
  __bf16* hs = (__bf16*)nxt((size_t)T_TOK * SI_DIM * 2);
  __bf16* so = (__bf16*)nxt((size_t)T_TOK * H_DIM * 2);
  float* gwt_f = (float*)nxt((size_t)E_NUM * H_DIM * 4);
  int* counts = (int*)nxt(64);
  int* offs = (int*)nxt(128);
  int* cursor = (int*)nxt(64);
  int* selE = (int*)nxt((size_t)T_TOK * K_TOP * 4);
  float* selW = (float*)nxt((size_t)T_TOK * K_TOP * 4);
  int* slot_of_tk = (int*)nxt((size_t)T_TOK * K_TOP * 4);
  int* tok_of_slot = (int*)nxt((size_t)T_TOK * K_TOP * 4);
  (void)ws_size;
  (void)in_sizes;
  (void)n_in;
  (void)out_size;

  dim3 tb(32, 8);
  transpose_cast_kernel<<<dim3(I_DIM / 32, H_DIM / 32, E_NUM), tb, 0, stream>>>(gate_w, gw_t,
                                                                                H_DIM, I_DIM);
  transpose_cast_kernel<<<dim3(I_DIM / 32, H_DIM / 32, E_NUM), tb, 0, stream>>>(up_w, uw_t, H_DIM,
                                                                                I_DIM);
  transpose_cast_kernel<<<dim3(H_DIM / 32, I_DIM / 32, E_NUM), tb, 0, stream>>>(down_w, dw_t,
                                                                                I_DIM, H_DIM);
  transpose_cast_kernel<<<dim3(SI_DIM / 32, H_DIM / 32, 1), tb, 0, stream>>>(sgw, sgw_t, H_DIM,
                                                                             SI_DIM);
  transpose_cast_kernel<<<dim3(SI_DIM / 32, H_DIM / 32, 1), tb, 0, stream>>>(suw, suw_t, H_DIM,
                                                                             SI_DIM);
  transpose_cast_kernel<<<dim3(H_DIM / 32, SI_DIM / 32, 1), tb, 0, stream>>>(sdw, sdw_t, SI_DIM,
                                                                             H_DIM);

  transpose_gw_kernel<<<64, 256, 0, stream>>>(gate_weight, gwt_f);
  cast_bf16_kernel<<<(T_TOK * H_DIM / 8) / 256, 256, 0, stream>>>(x, x_bf,
                                                                  (long)T_TOK * H_DIM / 8);
  zero_counts_kernel<<<1, 64, 0, stream>>>(counts);
  router_kernel<<<T_TOK, 256, 0, stream>>>(x, gwt_f, corr_bias, logits_out, counts, selE, selW);
  scan_kernel<<<1, 64, 0, stream>>>(counts, offs, cursor);
  place_kernel<<<T_TOK / 256, 256, 0, stream>>>(selE, cursor, slot_of_tk, tok_of_slot);

  gemm_bf16<<<dim3(8, 16, E_NUM), 256, 0, stream>>>(x_bf, gw_t, uw_t, g_buf, u_buf, tok_of_slot,
                                                    counts, offs, (size_t)I_DIM * H_DIM, 0, I_DIM,
                                                    H_DIM);
  silu_mul_kernel<<<(T_TOK * K_TOP * I_DIM / 8) / 256, 256, 0, stream>>>(
      g_buf, u_buf, he, (long)T_TOK * K_TOP * I_DIM / 8);
  gemm_bf16<<<dim3(8, 16, E_NUM), 256, 0, stream>>>(he, dw_t, nullptr, eo, nullptr, nullptr,
                                                    counts, offs, (size_t)H_DIM * I_DIM, 0, H_DIM,
                                                    I_DIM);

  gemm_bf16<<<dim3(16, 16, 1), 256, 0, stream>>>(x_bf, sgw_t, suw_t, gs_buf, us_buf, nullptr,
                                                 nullptr, nullptr, 0, T_TOK, SI_DIM, H_DIM);
  silu_mul_kernel<<<(T_TOK * SI_DIM / 8) / 256, 256, 0, stream>>>(gs_buf, us_buf, hs,
                                                                  (long)T_TOK * SI_DIM / 8);
  gemm_bf16<<<dim3(8, 16, 1), 256, 0, stream>>>(hs, sdw_t, nullptr, so, nullptr, nullptr, nullptr,
                                                nullptr, 0, T_TOK, H_DIM, SI_DIM);

  combine_kernel<<<(T_TOK * H_DIM / 4) / 256, 256, 0, stream>>>(eo, so, slot_of_tk, selW, out);
}

// Round 4
// 220.766 us; speedup vs baseline: 1.5161x; 1.3765x over previous
//
#include <hip/hip_runtime.h>
#include <hip/hip_bf16.h>

#define T_TOK 2048
#define H_DIM 1024
#define E_NUM 16
#define I_DIM 512
#define K_TOP 4
#define SI_DIM 1024

typedef __bf16 bf16x8 __attribute__((ext_vector_type(8)));
typedef __bf16 bf16x4 __attribute__((ext_vector_type(4)));
typedef float f32x4 __attribute__((ext_vector_type(4)));

#define GL2L(g, l)                                                                       \
  __builtin_amdgcn_global_load_lds((const __attribute__((address_space(1))) void*)(g),   \
                                   (__attribute__((address_space(3))) void*)(l), 16, 0, 0)

// ---------------- transpose gate_weight [H,E] -> [E,H] (tiny) ----------------
__global__ void transpose_gw_kernel(const float* __restrict__ in, float* __restrict__ out) {
  int idx = blockIdx.x * 256 + threadIdx.x;  // 16384
  int e = idx >> 10, h = idx & 1023;
  out[idx] = in[h * E_NUM + e];
}

// ---------------- transpose + cast fp32 [Z,R,C] -> bf16 [Z,C,R] ----------------
__global__ void transpose_cast_kernel(const float* __restrict__ in, __bf16* __restrict__ out,
                                      int R, int C) {
  __shared__ float tile[32][33];
  int z = blockIdx.z;
  int c0 = blockIdx.x * 32, r0 = blockIdx.y * 32;
  const float* ip = in + (size_t)z * R * C;
  __bf16* op = out + (size_t)z * R * C;
  int tx = threadIdx.x, ty = threadIdx.y;  // 32 x 8
#pragma unroll
  for (int j = 0; j < 4; j++) tile[ty + 8 * j][tx] = ip[(size_t)(r0 + ty + 8 * j) * C + c0 + tx];
  __syncthreads();
#pragma unroll
  for (int j = 0; j < 4; j++)
    op[(size_t)(c0 + ty + 8 * j) * R + r0 + tx] = (__bf16)tile[tx][ty + 8 * j];
}

// ---------------- cast fp32 -> bf16, vectorized ----------------
__global__ void cast_bf16_kernel(const float* __restrict__ in, __bf16* __restrict__ out, long n8) {
  long i = blockIdx.x * (long)blockDim.x + threadIdx.x;
  if (i >= n8) return;
  float4 v0 = *(const float4*)(in + i * 8);
  float4 v1 = *(const float4*)(in + i * 8 + 4);
  bf16x8 o;
  o[0] = (__bf16)v0.x;
  o[1] = (__bf16)v0.y;
  o[2] = (__bf16)v0.z;
  o[3] = (__bf16)v0.w;
  o[4] = (__bf16)v1.x;
  o[5] = (__bf16)v1.y;
  o[6] = (__bf16)v1.z;
  o[7] = (__bf16)v1.w;
  *(bf16x8*)(out + i * 8) = o;
}

// ---------------- router: one block (4 waves) per token, NO atomics ----------------
__global__ __launch_bounds__(256) void router_kernel(
    const float* __restrict__ x, const float* __restrict__ gwt, const float* __restrict__ cbias,
    float* __restrict__ logits_out, int* __restrict__ selE, float* __restrict__ selW) {
  int t = blockIdx.x;
  int tid = threadIdx.x;
  int wid = tid >> 6, lane = tid & 63;
  int e = lane >> 2, cl = lane & 3;
  int c = wid * 4 + cl;  // 0..15
  const float* xr = x + (size_t)t * H_DIM + c * 64;
  const float* gr = gwt + (size_t)e * H_DIM + c * 64;
  float a0 = 0.f, a1 = 0.f, a2 = 0.f, a3 = 0.f;
#pragma unroll
  for (int j = 0; j < 16; j++) {
    float4 xv = *(const float4*)(xr + j * 4);
    float4 gv = *(const float4*)(gr + j * 4);
    a0 = fmaf(xv.x, gv.x, a0);
    a1 = fmaf(xv.y, gv.y, a1);
    a2 = fmaf(xv.z, gv.z, a2);
    a3 = fmaf(xv.w, gv.w, a3);
  }
  float a = (a0 + a1) + (a2 + a3);
  a += __shfl_xor(a, 1);
  a += __shfl_xor(a, 2);
  __shared__ float part[4][16];
  if (cl == 0) part[wid][e] = a;
  __syncthreads();
  if (wid != 0) return;
  float logit = -1e30f;
  if (lane < E_NUM)
    logit = (part[0][lane] + part[1][lane]) + (part[2][lane] + part[3][lane]);
  if (lane < E_NUM) logits_out[(size_t)t * E_NUM + lane] = logit;
  float m = logit;
#pragma unroll
  for (int mk = 8; mk >= 1; mk >>= 1) m = fmaxf(m, __shfl_xor(m, mk));
  float p = __expf(logit - m);
  float s = p;
#pragma unroll
  for (int mk = 8; mk >= 1; mk >>= 1) s += __shfl_xor(s, mk);
  p /= s;
  float score = (lane < E_NUM) ? p + cbias[lane] : -1e30f;
  int sel[K_TOP];
  float w[K_TOP];
#pragma unroll
  for (int k = 0; k < K_TOP; k++) {
    float bv = score;
    int bi = (lane < E_NUM) ? lane : 999;
#pragma unroll
    for (int mk = 1; mk <= 8; mk <<= 1) {
      float ov = __shfl_xor(bv, mk);
      int oi = __shfl_xor(bi, mk);
      if (ov > bv || (ov == bv && oi < bi)) {
        bv = ov;
        bi = oi;
      }
    }
    sel[k] = bi;
    w[k] = __shfl(p, bi);
    if (lane == bi) score = -1e30f;
  }
  if (lane == 0) {
    float wsum = fmaxf(w[0] + w[1] + w[2] + w[3], 1e-12f);
#pragma unroll
    for (int k = 0; k < K_TOP; k++) {
      selE[t * K_TOP + k] = sel[k];
      selW[t * K_TOP + k] = w[k] / wsum;
    }
  }
}

// ---------------- count + place, ONE block, ballot-based, zero global atomics ----------
// entry = r*1024 + tid  (r=0..7), token = entry>>2. Slot order within an expert is
// (round, wave, lane) -- deterministic, consistent between slot_of_tk and tok_of_slot.
__global__ __launch_bounds__(1024) void count_place_kernel(
    const int* __restrict__ selE, int* __restrict__ counts, int* __restrict__ offs,
    int* __restrict__ slot_of_tk, int* __restrict__ tok_of_slot) {
  int tid = threadIdx.x;
  int wv = tid >> 6, lane = tid & 63;
  unsigned long long lt = (1ULL << lane) - 1ULL;
  __shared__ int wcnt[16][16];
  __shared__ int wbase[16][16];
  __shared__ int glob[16];
  __shared__ int offsh[16];
  if (tid < 16) glob[tid] = 0;
  __syncthreads();
  int ex[8], rk[8];
#pragma unroll
  for (int r = 0; r < 8; r++) {
    int e = selE[r * 1024 + tid];
    ex[r] = e;
    int rank = 0;
#pragma unroll
    for (int q = 0; q < 16; q++) {
      unsigned long long b = __ballot(e == q);
      int c = __popcll(b & lt);
      if (e == q) rank = c;
      if (lane == q) wcnt[wv][q] = __popcll(b);
    }
    __syncthreads();
    if (wv == 0 && lane < 16) {
      int run = glob[lane];
#pragma unroll
      for (int w = 0; w < 16; w++) {
        wbase[w][lane] = run;
        run += wcnt[w][lane];
      }
      glob[lane] = run;
    }
    __syncthreads();
    rk[r] = rank + wbase[wv][e];
    __syncthreads();
  }
  if (wv == 0 && lane == 0) {
    int s = 0;
#pragma unroll
    for (int q = 0; q < 16; q++) {
      offsh[q] = s;
      s += glob[q];
    }
  }
  __syncthreads();
  if (tid < 16) {
    counts[tid] = glob[tid];
    offs[tid] = offsh[tid];
  }
#pragma unroll
  for (int r = 0; r < 8; r++) {
    int entry = r * 1024 + tid;
    int slot = offsh[ex[r]] + rk[r];
    slot_of_tk[entry] = slot;
    tok_of_slot[slot] = entry >> 2;
  }
}

// ---------------- bf16 MFMA GEMM, 128x128 tile, BK=32 (m97 structure) ----------------
__global__ __launch_bounds__(256, 2) void gemm_bf16(
    const __bf16* __restrict__ A, const __bf16* __restrict__ B, const __bf16* __restrict__ Bu,
    __bf16* __restrict__ C, __bf16* __restrict__ Cu, const int* __restrict__ tokIdx,
    const int* __restrict__ cntPtr, const int* __restrict__ offPtr, size_t strideB, int Mfixed,
    int N, int K) {
  int z = blockIdx.z;
  int M = cntPtr ? cntPtr[z] : Mfixed;
  int m0 = blockIdx.y * 128;
  if (m0 >= M) return;
  const __bf16* Bp = B;
  __bf16* Cp = C;
  int nb = blockIdx.x;
  int NB = N >> 7;
  if (Bu && nb >= NB) {
    Bp = Bu;
    Cp = Cu;
    nb -= NB;
  }
  int n0 = nb << 7;
  int rowOff = offPtr ? offPtr[z] : 0;
  Bp += (size_t)z * strideB;

  __shared__ __align__(16) __bf16 Alds[128 * 32];
  __shared__ __align__(16) __bf16 Blds[128 * 32];

  int tid = threadIdx.x;
  int wave = tid >> 6, lane = tid & 63;
  int sRow0 = wave * 16 + (lane >> 2);
  int sRow1 = sRow0 + 64;
  int sCol = (lane & 3) * 8;

  auto aIdx = [&](int r) -> size_t {
    int rr = r < M - 1 ? r : M - 1;
    int rg = rowOff + rr;
    int ar = tokIdx ? tokIdx[rg] : rg;
    return (size_t)ar * K;
  };
  size_t aB0 = aIdx(m0 + sRow0) + sCol;
  size_t aB1 = aIdx(m0 + sRow1) + sCol;
  size_t bB0 = (size_t)(n0 + sRow0) * K + sCol;
  size_t bB1 = (size_t)(n0 + sRow1) * K + sCol;

  __bf16* ldsA0 = &Alds[wave * 512];
  __bf16* ldsA1 = &Alds[(wave + 4) * 512];
  __bf16* ldsB0 = &Blds[wave * 512];
  __bf16* ldsB1 = &Blds[(wave + 4) * 512];

  int wm = (wave >> 1) * 64, wn = (wave & 1) * 64;
  int rl = lane & 15, gq = lane >> 4;

  f32x4 acc[4][4] = {};

  for (int k0 = 0; k0 < K; k0 += 32) {
    GL2L(A + aB0 + k0, ldsA0);
    GL2L(A + aB1 + k0, ldsA1);
    GL2L(Bp + bB0 + k0, ldsB0);
    GL2L(Bp + bB1 + k0, ldsB1);
    __syncthreads();
    bf16x8 af[4], bfr[4];
#pragma unroll
    for (int m = 0; m < 4; m++) af[m] = *(const bf16x8*)&Alds[(wm + m * 16 + rl) * 32 + gq * 8];
#pragma unroll
    for (int n = 0; n < 4; n++) bfr[n] = *(const bf16x8*)&Blds[(wn + n * 16 + rl) * 32 + gq * 8];
#pragma unroll
    for (int m = 0; m < 4; m++)
#pragma unroll
      for (int n = 0; n < 4; n++)
        acc[m][n] = __builtin_amdgcn_mfma_f32_16x16x32_bf16(af[m], bfr[n], acc[m][n], 0, 0, 0);
    __syncthreads();
  }

#pragma unroll
  for (int m = 0; m < 4; m++) {
#pragma unroll
    for (int b = 0; b < 4; b++) {
      int row = m0 + wm + m * 16 + gq * 4 + b;
      if (row < M) {
        size_t rb = (size_t)(rowOff + row) * N + n0 + wn + rl;
#pragma unroll
        for (int n = 0; n < 4; n++) Cp[rb + n * 16] = (__bf16)acc[m][n][b];
      }
    }
  }
}

// ---------------- silu(g)*u elementwise ----------------
__global__ void silu_mul_kernel(const __bf16* __restrict__ g, const __bf16* __restrict__ u,
                                __bf16* __restrict__ h, long n8) {
  long i = blockIdx.x * (long)blockDim.x + threadIdx.x;
  if (i >= n8) return;
  bf16x8 gv = *(const bf16x8*)(g + i * 8);
  bf16x8 uv = *(const bf16x8*)(u + i * 8);
  bf16x8 hv;
#pragma unroll
  for (int j = 0; j < 8; j++) {
    float gf = (float)gv[j];
    float s = gf / (1.f + __expf(-gf));
    hv[j] = (__bf16)(s * (float)uv[j]);
  }
  *(bf16x8*)(h + i * 8) = hv;
}

// ---------------- combine: out = shared + sum_k w_k * eo[slot_k] ----------------
__global__ void combine_kernel(const __bf16* __restrict__ eo, const __bf16* __restrict__ so,
                               const int* __restrict__ slot_of_tk, const float* __restrict__ selW,
                               float* __restrict__ out) {
  int idx = blockIdx.x * blockDim.x + threadIdx.x;
  int t = idx >> 8;
  int h4 = (idx & 255) * 4;
  if (t >= T_TOK) return;
  bf16x4 sv = *(const bf16x4*)(so + (size_t)t * H_DIM + h4);
  float a0 = (float)sv[0], a1 = (float)sv[1], a2 = (float)sv[2], a3 = (float)sv[3];
#pragma unroll
  for (int k = 0; k < K_TOP; k++) {
    int slot = slot_of_tk[t * K_TOP + k];
    float w = selW[t * K_TOP + k];
    bf16x4 ev = *(const bf16x4*)(eo + (size_t)slot * H_DIM + h4);
    a0 += w * (float)ev[0];
    a1 += w * (float)ev[1];
    a2 += w * (float)ev[2];
    a3 += w * (float)ev[3];
  }
  *(float4*)(out + (size_t)t * H_DIM + h4) = make_float4(a0, a1, a2, a3);
}

extern "C" void kernel_launch(void* const* d_in, const int* in_sizes, int n_in, void* d_out,
                              int out_size, void* d_ws, size_t ws_size, hipStream_t stream) {
  const float* x = (const float*)d_in[0];
  const float* gate_weight = (const float*)d_in[1];
  const float* corr_bias = (const float*)d_in[2];
  const float* gate_w = (const float*)d_in[3];
  const float* up_w = (const float*)d_in[4];
  const float* down_w = (const float*)d_in[5];
  const float* sgw = (const float*)d_in[6];
  const float* suw = (const float*)d_in[7];
  const float* sdw = (const float*)d_in[8];
  float* out = (float*)d_out;
  float* logits_out = out + (size_t)T_TOK * H_DIM;

  char* wsb = (char*)d_ws;
  size_t o = 0;
  auto nxt = [&](size_t bytes) -> void* {
    void* p = wsb + o;
    o += (bytes + 1023) & ~(size_t)1023;
    return p;
  };
  __bf16* x_bf = (__bf16*)nxt((size_t)T_TOK * H_DIM * 2);
  __bf16* gw_t = (__bf16*)nxt((size_t)E_NUM * I_DIM * H_DIM * 2);  // [E, I, H]
  __bf16* uw_t = (__bf16*)nxt((size_t)E_NUM * I_DIM * H_DIM * 2);
  __bf16* dw_t = (__bf16*)nxt((size_t)E_NUM * H_DIM * I_DIM * 2);  // [E, H, I]
  __bf16* sgw_t = (__bf16*)nxt((size_t)SI_DIM * H_DIM * 2);        // [SI, H]
  __bf16* suw_t = (__bf16*)nxt((size_t)SI_DIM * H_DIM * 2);
  __bf16* sdw_t = (__bf16*)nxt((size_t)H_DIM * SI_DIM * 2);  // [H, SI]
  __bf16* g_buf = (__bf16*)nxt((size_t)T_TOK * K_TOP * I_DIM * 2);
  __bf16* u_buf = (__bf16*)nxt((size_t)T_TOK * K_TOP * I_DIM * 2);
  __bf16* he = (__bf16*)nxt((size_t)T_TOK * K_TOP * I_DIM * 2);
  __bf16* eo = (__bf16*)nxt((size_t)T_TOK * K_TOP * H_DIM * 2);
  __bf16* gs_buf = (__bf16*)nxt((size_t)T_TOK * SI_DIM * 2);
  __bf16* us_buf = (__bf16*)nxt((size_t)T_TOK * SI_DIM * 2);
  __bf16* hs = (__bf16*)nxt((size_t)T_TOK * SI_DIM * 2);
  __bf16* so = (__bf16*)nxt((size_t)T_TOK * H_DIM * 2);
  float* gwt_f = (float*)nxt((size_t)E_NUM * H_DIM * 4);
  int* counts = (int*)nxt(64);
  int* offs = (int*)nxt(128);
  int* selE = (int*)nxt((size_t)T_TOK * K_TOP * 4);
  float* selW = (float*)nxt((size_t)T_TOK * K_TOP * 4);
  int* slot_of_tk = (int*)nxt((size_t)T_TOK * K_TOP * 4);
  int* tok_of_slot = (int*)nxt((size_t)T_TOK * K_TOP * 4);
  (void)ws_size;
  (void)in_sizes;
  (void)n_in;
  (void)out_size;

  dim3 tb(32, 8);
  transpose_cast_kernel<<<dim3(I_DIM / 32, H_DIM / 32, E_NUM), tb, 0, stream>>>(gate_w, gw_t,
                                                                                H_DIM, I_DIM);
  transpose_cast_kernel<<<dim3(I_DIM / 32, H_DIM / 32, E_NUM), tb, 0, stream>>>(up_w, uw_t, H_DIM,
                                                                                I_DIM);
  transpose_cast_kernel<<<dim3(H_DIM / 32, I_DIM / 32, E_NUM), tb, 0, stream>>>(down_w, dw_t,
                                                                                I_DIM, H_DIM);
  transpose_cast_kernel<<<dim3(SI_DIM / 32, H_DIM / 32, 1), tb, 0, stream>>>(sgw, sgw_t, H_DIM,
                                                                             SI_DIM);
  transpose_cast_kernel<<<dim3(SI_DIM / 32, H_DIM / 32, 1), tb, 0, stream>>>(suw, suw_t, H_DIM,
                                                                             SI_DIM);
  transpose_cast_kernel<<<dim3(H_DIM / 32, SI_DIM / 32, 1), tb, 0, stream>>>(sdw, sdw_t, SI_DIM,
                                                                             H_DIM);

  transpose_gw_kernel<<<64, 256, 0, stream>>>(gate_weight, gwt_f);
  cast_bf16_kernel<<<(T_TOK * H_DIM / 8) / 256, 256, 0, stream>>>(x, x_bf,
                                                                  (long)T_TOK * H_DIM / 8);
  router_kernel<<<T_TOK, 256, 0, stream>>>(x, gwt_f, corr_bias, logits_out, selE, selW);
  count_place_kernel<<<1, 1024, 0, stream>>>(selE, counts, offs, slot_of_tk, tok_of_slot);

  gemm_bf16<<<dim3(8, 16, E_NUM), 256, 0, stream>>>(x_bf, gw_t, uw_t, g_buf, u_buf, tok_of_slot,
                                                    counts, offs, (size_t)I_DIM * H_DIM, 0, I_DIM,
                                                    H_DIM);
  silu_mul_kernel<<<(T_TOK * K_TOP * I_DIM / 8) / 256, 256, 0, stream>>>(
      g_buf, u_buf, he, (long)T_TOK * K_TOP * I_DIM / 8);
  gemm_bf16<<<dim3(8, 16, E_NUM), 256, 0, stream>>>(he, dw_t, nullptr, eo, nullptr, nullptr,
                                                    counts, offs, (size_t)H_DIM * I_DIM, 0, H_DIM,
                                                    I_DIM);

  gemm_bf16<<<dim3(16, 16, 1), 256, 0, stream>>>(x_bf, sgw_t, suw_t, gs_buf, us_buf, nullptr,
                                                 nullptr, nullptr, 0, T_TOK, SI_DIM, H_DIM);
  silu_mul_kernel<<<(T_TOK * SI_DIM / 8) / 256, 256, 0, stream>>>(gs_buf, us_buf, hs,
                                                                  (long)T_TOK * SI_DIM / 8);
  gemm_bf16<<<dim3(8, 16, 1), 256, 0, stream>>>(hs, sdw_t, nullptr, so, nullptr, nullptr, nullptr,
                                                nullptr, 0, T_TOK, H_DIM, SI_DIM);

  combine_kernel<<<(T_TOK * H_DIM / 4) / 256, 256, 0, stream>>>(eo, so, slot_of_tk, selW, out);
}

// Round 5
// 185.815 us; speedup vs baseline: 1.8012x; 1.1881x over previous
//
#include <hip/hip_runtime.h>
#include <hip/hip_bf16.h>

#define T_TOK 2048
#define H_DIM 1024
#define E_NUM 16
#define I_DIM 512
#define K_TOP 4
#define SI_DIM 1024

typedef __bf16 bf16x8 __attribute__((ext_vector_type(8)));
typedef __bf16 bf16x4 __attribute__((ext_vector_type(4)));
typedef float f32x4 __attribute__((ext_vector_type(4)));

#define GL2L(g, l)                                                                       \
  __builtin_amdgcn_global_load_lds((const __attribute__((address_space(1))) void*)(g),   \
                                   (__attribute__((address_space(3))) void*)(l), 16, 0, 0)

// ---------------- transpose gate_weight [H,E] -> [E,H] (tiny) ----------------
__global__ void transpose_gw_kernel(const float* __restrict__ in, float* __restrict__ out) {
  int idx = blockIdx.x * 256 + threadIdx.x;  // 16384
  int e = idx >> 10, h = idx & 1023;
  out[idx] = in[h * E_NUM + e];
}

// ---------------- transpose + cast fp32 [Z,R,C] -> bf16 [Z,C,R] ----------------
__global__ void transpose_cast_kernel(const float* __restrict__ in, __bf16* __restrict__ out,
                                      int R, int C) {
  __shared__ float tile[32][33];
  int z = blockIdx.z;
  int c0 = blockIdx.x * 32, r0 = blockIdx.y * 32;
  const float* ip = in + (size_t)z * R * C;
  __bf16* op = out + (size_t)z * R * C;
  int tx = threadIdx.x, ty = threadIdx.y;  // 32 x 8
#pragma unroll
  for (int j = 0; j < 4; j++) tile[ty + 8 * j][tx] = ip[(size_t)(r0 + ty + 8 * j) * C + c0 + tx];
  __syncthreads();
#pragma unroll
  for (int j = 0; j < 4; j++)
    op[(size_t)(c0 + ty + 8 * j) * R + r0 + tx] = (__bf16)tile[tx][ty + 8 * j];
}

// ---------------- cast fp32 -> bf16, vectorized ----------------
__global__ void cast_bf16_kernel(const float* __restrict__ in, __bf16* __restrict__ out, long n8) {
  long i = blockIdx.x * (long)blockDim.x + threadIdx.x;
  if (i >= n8) return;
  float4 v0 = *(const float4*)(in + i * 8);
  float4 v1 = *(const float4*)(in + i * 8 + 4);
  bf16x8 o;
  o[0] = (__bf16)v0.x;
  o[1] = (__bf16)v0.y;
  o[2] = (__bf16)v0.z;
  o[3] = (__bf16)v0.w;
  o[4] = (__bf16)v1.x;
  o[5] = (__bf16)v1.y;
  o[6] = (__bf16)v1.z;
  o[7] = (__bf16)v1.w;
  *(bf16x8*)(out + i * 8) = o;
}

// ---------------- router: one block (4 waves) per token, NO atomics ----------------
__global__ __launch_bounds__(256) void router_kernel(
    const float* __restrict__ x, const float* __restrict__ gwt, const float* __restrict__ cbias,
    float* __restrict__ logits_out, int* __restrict__ selE, float* __restrict__ selW) {
  int t = blockIdx.x;
  int tid = threadIdx.x;
  int wid = tid >> 6, lane = tid & 63;
  int e = lane >> 2, cl = lane & 3;
  int c = wid * 4 + cl;  // 0..15
  const float* xr = x + (size_t)t * H_DIM + c * 64;
  const float* gr = gwt + (size_t)e * H_DIM + c * 64;
  float a0 = 0.f, a1 = 0.f, a2 = 0.f, a3 = 0.f;
#pragma unroll
  for (int j = 0; j < 16; j++) {
    float4 xv = *(const float4*)(xr + j * 4);
    float4 gv = *(const float4*)(gr + j * 4);
    a0 = fmaf(xv.x, gv.x, a0);
    a1 = fmaf(xv.y, gv.y, a1);
    a2 = fmaf(xv.z, gv.z, a2);
    a3 = fmaf(xv.w, gv.w, a3);
  }
  float a = (a0 + a1) + (a2 + a3);
  a += __shfl_xor(a, 1);
  a += __shfl_xor(a, 2);
  __shared__ float part[4][16];
  if (cl == 0) part[wid][e] = a;
  __syncthreads();
  if (wid != 0) return;
  float logit = -1e30f;
  if (lane < E_NUM)
    logit = (part[0][lane] + part[1][lane]) + (part[2][lane] + part[3][lane]);
  if (lane < E_NUM) logits_out[(size_t)t * E_NUM + lane] = logit;
  float m = logit;
#pragma unroll
  for (int mk = 8; mk >= 1; mk >>= 1) m = fmaxf(m, __shfl_xor(m, mk));
  float p = __expf(logit - m);
  float s = p;
#pragma unroll
  for (int mk = 8; mk >= 1; mk >>= 1) s += __shfl_xor(s, mk);
  p /= s;
  float score = (lane < E_NUM) ? p + cbias[lane] : -1e30f;
  int sel[K_TOP];
  float w[K_TOP];
#pragma unroll
  for (int k = 0; k < K_TOP; k++) {
    float bv = score;
    int bi = (lane < E_NUM) ? lane : 999;
#pragma unroll
    for (int mk = 1; mk <= 8; mk <<= 1) {
      float ov = __shfl_xor(bv, mk);
      int oi = __shfl_xor(bi, mk);
      if (ov > bv || (ov == bv && oi < bi)) {
        bv = ov;
        bi = oi;
      }
    }
    sel[k] = bi;
    w[k] = __shfl(p, bi);
    if (lane == bi) score = -1e30f;
  }
  if (lane == 0) {
    float wsum = fmaxf(w[0] + w[1] + w[2] + w[3], 1e-12f);
#pragma unroll
    for (int k = 0; k < K_TOP; k++) {
      selE[t * K_TOP + k] = sel[k];
      selW[t * K_TOP + k] = w[k] / wsum;
    }
  }
}

// ---------------- count + place, ONE block, ballot-based, zero global atomics ----------
__global__ __launch_bounds__(1024) void count_place_kernel(
    const int* __restrict__ selE, int* __restrict__ counts, int* __restrict__ offs,
    int* __restrict__ slot_of_tk, int* __restrict__ tok_of_slot) {
  int tid = threadIdx.x;
  int wv = tid >> 6, lane = tid & 63;
  unsigned long long lt = (1ULL << lane) - 1ULL;
  __shared__ int wcnt[16][16];
  __shared__ int wbase[16][16];
  __shared__ int glob[16];
  __shared__ int offsh[16];
  if (tid < 16) glob[tid] = 0;
  __syncthreads();
  int ex[8], rk[8];
#pragma unroll
  for (int r = 0; r < 8; r++) {
    int e = selE[r * 1024 + tid];
    ex[r] = e;
    int rank = 0;
#pragma unroll
    for (int q = 0; q < 16; q++) {
      unsigned long long b = __ballot(e == q);
      int c = __popcll(b & lt);
      if (e == q) rank = c;
      if (lane == q) wcnt[wv][q] = __popcll(b);
    }
    __syncthreads();
    if (wv == 0 && lane < 16) {
      int run = glob[lane];
#pragma unroll
      for (int w = 0; w < 16; w++) {
        wbase[w][lane] = run;
        run += wcnt[w][lane];
      }
      glob[lane] = run;
    }
    __syncthreads();
    rk[r] = rank + wbase[wv][e];
    __syncthreads();
  }
  if (wv == 0 && lane == 0) {
    int s = 0;
#pragma unroll
    for (int q = 0; q < 16; q++) {
      offsh[q] = s;
      s += glob[q];
    }
  }
  __syncthreads();
  if (tid < 16) {
    counts[tid] = glob[tid];
    offs[tid] = offsh[tid];
  }
#pragma unroll
  for (int r = 0; r < 8; r++) {
    int entry = r * 1024 + tid;
    int slot = offsh[ex[r]] + rk[r];
    slot_of_tk[entry] = slot;
    tok_of_slot[slot] = entry >> 2;
  }
}

// ---------------- 128x128 tile, BK=64, XOR-swizzled LDS (swizzle on SOURCE + READ) ----
// GL2L writes linearly (base + lane*16B). Lane l stages (row = base+l>>3, chunk = l&7),
// reading global chunk (l&7)^(row&7). Reader fetches logical chunk q at physical
// q^(row&7): conflict-free across 8 rows (2-way across 16 = free).
__device__ __forceinline__ void gemm_tile(const __bf16* __restrict__ A,
                                          const int* __restrict__ tokIdx, int rowOff, int M,
                                          int m0, int n0, int K, int ldC,
                                          const __bf16* __restrict__ Bp, __bf16* __restrict__ Cp,
                                          __bf16* Alds, __bf16* Blds) {
  int tid = threadIdx.x;
  int wave = tid >> 6, lane = tid & 63;
  int rsub = lane >> 3, chunk = lane & 7;
  int sch = (chunk ^ rsub) * 8;  // swizzled source offset (elems)
  size_t aB[4], bB[4];
#pragma unroll
  for (int j = 0; j < 4; j++) {
    int r = wave * 32 + j * 8 + rsub;
    int ar = m0 + r;
    ar = ar < M - 1 ? ar : M - 1;
    int grow = tokIdx ? tokIdx[rowOff + ar] : rowOff + ar;
    aB[j] = (size_t)grow * K + sch;
    bB[j] = (size_t)(n0 + r) * K + sch;
  }
  int wm = (wave >> 1) * 64, wn = (wave & 1) * 64;
  int rl = lane & 15, gq = lane >> 4;
  int xa = rl & 7;
  f32x4 acc[4][4] = {};
  for (int k0 = 0; k0 < K; k0 += 64) {
#pragma unroll
    for (int j = 0; j < 4; j++) {
      GL2L(A + aB[j] + k0, Alds + (wave * 32 + j * 8) * 64);
      GL2L(Bp + bB[j] + k0, Blds + (wave * 32 + j * 8) * 64);
    }
    __syncthreads();
    bf16x8 af[2][4], bfr[2][4];
#pragma unroll
    for (int s = 0; s < 2; s++) {
      int lc = ((s * 4 + gq) ^ xa) * 8;
#pragma unroll
      for (int m = 0; m < 4; m++)
        af[s][m] = *(const bf16x8*)&Alds[(wm + m * 16 + rl) * 64 + lc];
#pragma unroll
      for (int n = 0; n < 4; n++)
        bfr[s][n] = *(const bf16x8*)&Blds[(wn + n * 16 + rl) * 64 + lc];
    }
#pragma unroll
    for (int s = 0; s < 2; s++)
#pragma unroll
      for (int m = 0; m < 4; m++)
#pragma unroll
        for (int n = 0; n < 4; n++)
          acc[m][n] =
              __builtin_amdgcn_mfma_f32_16x16x32_bf16(af[s][m], bfr[s][n], acc[m][n], 0, 0, 0);
    __syncthreads();
  }
#pragma unroll
  for (int m = 0; m < 4; m++) {
#pragma unroll
    for (int b = 0; b < 4; b++) {
      int row = m0 + wm + m * 16 + gq * 4 + b;
      if (row < M) {
        size_t rb = (size_t)(rowOff + row) * ldC + n0 + wn + rl;
#pragma unroll
        for (int n = 0; n < 4; n++) Cp[rb + n * 16] = (__bf16)acc[m][n][b];
      }
    }
  }
}

// stage 1: expert gate+up (z<16, gathered A) + shared gate+up (z==16, identity A)
__global__ __launch_bounds__(256, 2) void gemm_stage1(
    const __bf16* __restrict__ x_bf, const int* __restrict__ tok_of_slot,
    const int* __restrict__ counts, const int* __restrict__ offs, const __bf16* __restrict__ gw_t,
    const __bf16* __restrict__ uw_t, const __bf16* __restrict__ sgw_t,
    const __bf16* __restrict__ suw_t, __bf16* __restrict__ g_buf, __bf16* __restrict__ u_buf,
    __bf16* __restrict__ gs_buf, __bf16* __restrict__ us_buf) {
  __shared__ __align__(16) __bf16 Alds[128 * 64];
  __shared__ __align__(16) __bf16 Blds[128 * 64];
  int z = blockIdx.z, bx = blockIdx.x, m0 = blockIdx.y * 128;
  if (z < E_NUM) {
    if (bx >= 8) return;
    int M = counts[z];
    if (m0 >= M) return;
    bool gate = bx < 4;
    const __bf16* Bp = (gate ? gw_t : uw_t) + (size_t)z * I_DIM * H_DIM;
    __bf16* Cp = gate ? g_buf : u_buf;
    gemm_tile(x_bf, tok_of_slot, offs[z], M, m0, (bx & 3) * 128, H_DIM, I_DIM, Bp, Cp, Alds,
              Blds);
  } else {
    bool gate = bx < 8;
    const __bf16* Bp = gate ? sgw_t : suw_t;
    __bf16* Cp = gate ? gs_buf : us_buf;
    gemm_tile(x_bf, nullptr, 0, T_TOK, m0, (bx & 7) * 128, H_DIM, SI_DIM, Bp, Cp, Alds, Blds);
  }
}

// stage 2: expert down (z<16) + shared down (z==16)
__global__ __launch_bounds__(256, 2) void gemm_stage2(
    const __bf16* __restrict__ he, const __bf16* __restrict__ hs, const int* __restrict__ counts,
    const int* __restrict__ offs, const __bf16* __restrict__ dw_t,
    const __bf16* __restrict__ sdw_t, __bf16* __restrict__ eo, __bf16* __restrict__ so) {
  __shared__ __align__(16) __bf16 Alds[128 * 64];
  __shared__ __align__(16) __bf16 Blds[128 * 64];
  int z = blockIdx.z, bx = blockIdx.x, m0 = blockIdx.y * 128;
  if (z < E_NUM) {
    int M = counts[z];
    if (m0 >= M) return;
    gemm_tile(he, nullptr, offs[z], M, m0, bx * 128, I_DIM, H_DIM,
              dw_t + (size_t)z * H_DIM * I_DIM, eo, Alds, Blds);
  } else {
    gemm_tile(hs, nullptr, 0, T_TOK, m0, bx * 128, SI_DIM, H_DIM, sdw_t, so, Alds, Blds);
  }
}

// ---------------- silu(g)*u elementwise (expert + shared merged) ----------------
__global__ void silu_mul_kernel(const __bf16* __restrict__ g, const __bf16* __restrict__ u,
                                __bf16* __restrict__ h, long n8) {
  long i = blockIdx.x * (long)blockDim.x + threadIdx.x;
  if (i >= n8) return;
  bf16x8 gv = *(const bf16x8*)(g + i * 8);
  bf16x8 uv = *(const bf16x8*)(u + i * 8);
  bf16x8 hv;
#pragma unroll
  for (int j = 0; j < 8; j++) {
    float gf = (float)gv[j];
    float s = gf / (1.f + __expf(-gf));
    hv[j] = (__bf16)(s * (float)uv[j]);
  }
  *(bf16x8*)(h + i * 8) = hv;
}

// ---------------- combine: out = shared + sum_k w_k * eo[slot_k] ----------------
__global__ void combine_kernel(const __bf16* __restrict__ eo, const __bf16* __restrict__ so,
                               const int* __restrict__ slot_of_tk, const float* __restrict__ selW,
                               float* __restrict__ out) {
  int idx = blockIdx.x * blockDim.x + threadIdx.x;
  int t = idx >> 8;
  int h4 = (idx & 255) * 4;
  if (t >= T_TOK) return;
  bf16x4 sv = *(const bf16x4*)(so + (size_t)t * H_DIM + h4);
  float a0 = (float)sv[0], a1 = (float)sv[1], a2 = (float)sv[2], a3 = (float)sv[3];
#pragma unroll
  for (int k = 0; k < K_TOP; k++) {
    int slot = slot_of_tk[t * K_TOP + k];
    float w = selW[t * K_TOP + k];
    bf16x4 ev = *(const bf16x4*)(eo + (size_t)slot * H_DIM + h4);
    a0 += w * (float)ev[0];
    a1 += w * (float)ev[1];
    a2 += w * (float)ev[2];
    a3 += w * (float)ev[3];
  }
  *(float4*)(out + (size_t)t * H_DIM + h4) = make_float4(a0, a1, a2, a3);
}

extern "C" void kernel_launch(void* const* d_in, const int* in_sizes, int n_in, void* d_out,
                              int out_size, void* d_ws, size_t ws_size, hipStream_t stream) {
  const float* x = (const float*)d_in[0];
  const float* gate_weight = (const float*)d_in[1];
  const float* corr_bias = (const float*)d_in[2];
  const float* gate_w = (const float*)d_in[3];
  const float* up_w = (const float*)d_in[4];
  const float* down_w = (const float*)d_in[5];
  const float* sgw = (const float*)d_in[6];
  const float* suw = (const float*)d_in[7];
  const float* sdw = (const float*)d_in[8];
  float* out = (float*)d_out;
  float* logits_out = out + (size_t)T_TOK * H_DIM;

  char* wsb = (char*)d_ws;
  size_t o = 0;
  auto nxt = [&](size_t bytes) -> void* {
    void* p = wsb + o;
    o += (bytes + 1023) & ~(size_t)1023;
    return p;
  };
  const size_t EXP_ELE = (size_t)T_TOK * K_TOP * I_DIM;  // 4M
  const size_t SH_ELE = (size_t)T_TOK * SI_DIM;          // 2M
  __bf16* x_bf = (__bf16*)nxt((size_t)T_TOK * H_DIM * 2);
  __bf16* gw_t = (__bf16*)nxt((size_t)E_NUM * I_DIM * H_DIM * 2);  // [E, I, H]
  __bf16* uw_t = (__bf16*)nxt((size_t)E_NUM * I_DIM * H_DIM * 2);
  __bf16* dw_t = (__bf16*)nxt((size_t)E_NUM * H_DIM * I_DIM * 2);  // [E, H, I]
  __bf16* sgw_t = (__bf16*)nxt((size_t)SI_DIM * H_DIM * 2);        // [SI, H]
  __bf16* suw_t = (__bf16*)nxt((size_t)SI_DIM * H_DIM * 2);
  __bf16* sdw_t = (__bf16*)nxt((size_t)H_DIM * SI_DIM * 2);  // [H, SI]
  __bf16* g_all = (__bf16*)nxt((EXP_ELE + SH_ELE) * 2);
  __bf16* u_all = (__bf16*)nxt((EXP_ELE + SH_ELE) * 2);
  __bf16* h_all = (__bf16*)nxt((EXP_ELE + SH_ELE) * 2);
  __bf16* eo = (__bf16*)nxt((size_t)T_TOK * K_TOP * H_DIM * 2);
  __bf16* so = (__bf16*)nxt((size_t)T_TOK * H_DIM * 2);
  float* gwt_f = (float*)nxt((size_t)E_NUM * H_DIM * 4);
  int* counts = (int*)nxt(64);
  int* offs = (int*)nxt(128);
  int* selE = (int*)nxt((size_t)T_TOK * K_TOP * 4);
  float* selW = (float*)nxt((size_t)T_TOK * K_TOP * 4);
  int* slot_of_tk = (int*)nxt((size_t)T_TOK * K_TOP * 4);
  int* tok_of_slot = (int*)nxt((size_t)T_TOK * K_TOP * 4);
  __bf16* g_buf = g_all;
  __bf16* gs_buf = g_all + EXP_ELE;
  __bf16* u_buf = u_all;
  __bf16* us_buf = u_all + EXP_ELE;
  __bf16* he = h_all;
  __bf16* hs = h_all + EXP_ELE;
  (void)ws_size;
  (void)in_sizes;
  (void)n_in;
  (void)out_size;

  dim3 tb(32, 8);
  transpose_cast_kernel<<<dim3(I_DIM / 32, H_DIM / 32, E_NUM), tb, 0, stream>>>(gate_w, gw_t,
                                                                                H_DIM, I_DIM);
  transpose_cast_kernel<<<dim3(I_DIM / 32, H_DIM / 32, E_NUM), tb, 0, stream>>>(up_w, uw_t, H_DIM,
                                                                                I_DIM);
  transpose_cast_kernel<<<dim3(H_DIM / 32, I_DIM / 32, E_NUM), tb, 0, stream>>>(down_w, dw_t,
                                                                                I_DIM, H_DIM);
  transpose_cast_kernel<<<dim3(SI_DIM / 32, H_DIM / 32, 1), tb, 0, stream>>>(sgw, sgw_t, H_DIM,
                                                                             SI_DIM);
  transpose_cast_kernel<<<dim3(SI_DIM / 32, H_DIM / 32, 1), tb, 0, stream>>>(suw, suw_t, H_DIM,
                                                                             SI_DIM);
  transpose_cast_kernel<<<dim3(H_DIM / 32, SI_DIM / 32, 1), tb, 0, stream>>>(sdw, sdw_t, SI_DIM,
                                                                             H_DIM);

  transpose_gw_kernel<<<64, 256, 0, stream>>>(gate_weight, gwt_f);
  cast_bf16_kernel<<<(T_TOK * H_DIM / 8) / 256, 256, 0, stream>>>(x, x_bf,
                                                                  (long)T_TOK * H_DIM / 8);
  router_kernel<<<T_TOK, 256, 0, stream>>>(x, gwt_f, corr_bias, logits_out, selE, selW);
  count_place_kernel<<<1, 1024, 0, stream>>>(selE, counts, offs, slot_of_tk, tok_of_slot);

  gemm_stage1<<<dim3(16, 16, E_NUM + 1), 256, 0, stream>>>(x_bf, tok_of_slot, counts, offs, gw_t,
                                                           uw_t, sgw_t, suw_t, g_buf, u_buf,
                                                           gs_buf, us_buf);
  silu_mul_kernel<<<(int)((EXP_ELE + SH_ELE) / 8 / 256), 256, 0, stream>>>(
      g_all, u_all, h_all, (long)(EXP_ELE + SH_ELE) / 8);
  gemm_stage2<<<dim3(8, 16, E_NUM + 1), 256, 0, stream>>>(he, hs, counts, offs, dw_t, sdw_t, eo,
                                                          so);

  combine_kernel<<<(T_TOK * H_DIM / 4) / 256, 256, 0, stream>>>(eo, so, slot_of_tk, selW, out);
}